// Round 1
// baseline (252.713 us; speedup 1.0000x reference)
//
#include <hip/hip_runtime.h>

typedef unsigned short u16;
typedef __bf16 bf16x8 __attribute__((ext_vector_type(8)));
typedef float f32x4 __attribute__((ext_vector_type(4)));

#define MFMA16(a, b, c) __builtin_amdgcn_mfma_f32_16x16x32_bf16(a, b, c, 0, 0, 0)

__device__ __forceinline__ u16 f2bf(float f) {
  unsigned int u = __float_as_uint(f);
  u += 0x7FFFu + ((u >> 16) & 1u);   // RNE to bf16
  return (u16)(u >> 16);
}

// async global->LDS, 16B per lane; lds base must be wave-uniform, HW writes base + lane*16
__device__ __forceinline__ void gld16(u16* lds, const u16* g) {
  __builtin_amdgcn_global_load_lds((const __attribute__((address_space(1))) void*)g,
                                   (__attribute__((address_space(3))) void*)lds,
                                   16, 0, 0);
}

// Exact integer replication of T5 bucketing (bidirectional, 32 buckets, max_dist 128).
// Thresholds are ceil(8*2^(j/2)); verified consistent with the reference's f32 math
// at the only integer-exact boundaries (16/32/64).
__device__ __forceinline__ int t5_bucket(int rp) {
  int ret = rp > 0 ? 16 : 0;
  int a = rp < 0 ? -rp : rp;
  int b;
  if      (a <  8) b = a;
  else if (a < 12) b = 8;
  else if (a < 16) b = 9;
  else if (a < 23) b = 10;
  else if (a < 32) b = 11;
  else if (a < 46) b = 12;
  else if (a < 64) b = 13;
  else if (a < 91) b = 14;
  else             b = 15;
  return ret + b;
}

// ---------------- fp32 -> bf16 convert of hidden_states ----------------
__global__ __launch_bounds__(256) void cvt_x(const float4* __restrict__ X,
                                             ushort4* __restrict__ Xb) {
  int g = blockIdx.x * 256 + threadIdx.x;
  float4 v = X[g];
  ushort4 o;
  o.x = f2bf(v.x); o.y = f2bf(v.y); o.z = f2bf(v.z); o.w = f2bf(v.w);
  Xb[g] = o;
}

// ---------------- weight convert + transpose: W[k][n] fp32 -> Wt[n][k] bf16 ----------------
__global__ __launch_bounds__(256) void wcvt(const float* __restrict__ w0, const float* __restrict__ w1,
                                            const float* __restrict__ w2, const float* __restrict__ w3,
                                            u16* __restrict__ out) {
  const int z = blockIdx.z;
  const float* W = (z == 0) ? w0 : (z == 1) ? w1 : (z == 2) ? w2 : w3;
  u16* O = out + z * 1048576;
  __shared__ __align__(16) u16 t[64 * 68];
  const int col = threadIdx.x & 63;
  const int rowo = threadIdx.x >> 6;
  const int n0 = blockIdx.x * 64, k0 = blockIdx.y * 64;
#pragma unroll
  for (int r = 0; r < 16; r++) {
    int kl = r * 4 + rowo;
    t[col * 68 + kl] = f2bf(W[(k0 + kl) * 1024 + n0 + col]);
  }
  __syncthreads();
#pragma unroll
  for (int r = 0; r < 16; r++) {
    int nl = r * 4 + rowo;
    O[(n0 + nl) * 1024 + k0 + col] = t[nl * 68 + col];
  }
}

// ---------------- 128x128 bf16 GEMM, C = A[4096x1024] @ Bt[1024x1024]^T ----------------
// modeSel: -1 -> mode = blockIdx.z (0:Q layout, 1:K layout, 2:Vt layout), 3 -> fp32 out
__global__ __launch_bounds__(256) void gemm128(const u16* __restrict__ A,
                                               const u16* __restrict__ BtBase,
                                               void* __restrict__ outp, int modeSel) {
  __shared__ __align__(16) u16 sA[128 * 64];
  __shared__ __align__(16) u16 sB[128 * 64];
  const int tid = threadIdx.x, lane = tid & 63, wave = tid >> 6;
  const int l15 = lane & 15, quad = lane >> 4;
  const int wm = (wave >> 1) * 64, wn = (wave & 1) * 64;
  const int m0 = blockIdx.y * 128, n0 = blockIdx.x * 128;
  const int z = blockIdx.z;
  const int mode = (modeSel < 0) ? z : modeSel;
  const u16* Bt = BtBase + ((modeSel < 0) ? z * 1048576 : 0);

  f32x4 acc[4][4];
  const f32x4 vz = {0.f, 0.f, 0.f, 0.f};
#pragma unroll
  for (int i = 0; i < 4; i++)
#pragma unroll
    for (int j = 0; j < 4; j++) acc[i][j] = vz;

  for (int kt = 0; kt < 16; kt++) {
    const int ka = kt * 64;
#pragma unroll
    for (int r = 0; r < 4; r++) {
      int cb = r * 256 + wave * 64;
      int cc = cb + lane;
      gld16(sA + cb * 8, A  + (m0 + (cc >> 3)) * 1024 + ka + (cc & 7) * 8);
      gld16(sB + cb * 8, Bt + (n0 + (cc >> 3)) * 1024 + ka + (cc & 7) * 8);
    }
    __syncthreads();
#pragma unroll
    for (int kk = 0; kk < 2; kk++) {
      bf16x8 af[4], bg[4];
#pragma unroll
      for (int mt = 0; mt < 4; mt++)
        af[mt] = *(const bf16x8*)(sA + (wm + mt * 16 + l15) * 64 + kk * 32 + quad * 8);
#pragma unroll
      for (int nt = 0; nt < 4; nt++)
        bg[nt] = *(const bf16x8*)(sB + (wn + nt * 16 + l15) * 64 + kk * 32 + quad * 8);
#pragma unroll
      for (int mt = 0; mt < 4; mt++)
#pragma unroll
        for (int nt = 0; nt < 4; nt++)
          acc[mt][nt] = MFMA16(af[mt], bg[nt], acc[mt][nt]);
    }
    __syncthreads();
  }

  if (mode == 3) {
    float* O = (float*)outp;
#pragma unroll
    for (int mt = 0; mt < 4; mt++)
#pragma unroll
      for (int nt = 0; nt < 4; nt++)
#pragma unroll
        for (int reg = 0; reg < 4; reg++) {
          int row = m0 + wm + mt * 16 + quad * 4 + reg;
          int col = n0 + wn + nt * 16 + l15;
          O[row * 1024 + col] = acc[mt][nt][reg];
        }
  } else {
    u16* O = (u16*)outp + z * 4194304;
#pragma unroll
    for (int mt = 0; mt < 4; mt++)
#pragma unroll
      for (int nt = 0; nt < 4; nt++)
#pragma unroll
        for (int reg = 0; reg < 4; reg++) {
          int row = m0 + wm + mt * 16 + quad * 4 + reg;   // m = b*1024 + s
          int col = n0 + wn + nt * 16 + l15;              // n = h*64 + dk
          int bb = row >> 10, s = row & 1023, hh = col >> 6, dk = col & 63;
          u16 val = f2bf(acc[mt][nt][reg]);
          if (mode == 2) O[((bb * 16 + hh) * 64 + dk) * 1024 + s] = val;        // Vt[b,h,dk,s]
          else           O[(bb * 16 + hh) * 65536 + s * 64 + dk] = val;         // Q/K[b,h,s,dk]
        }
  }
}

// ---------------- flash attention: one block = one (b,h), 128 q-rows ----------------
__global__ __launch_bounds__(256) void attn(const u16* __restrict__ Q, const u16* __restrict__ K,
                                            const u16* __restrict__ V, const float* __restrict__ emb,
                                            u16* __restrict__ ctx) {
  __shared__ __align__(16) u16 sQ[128 * 64];
  __shared__ __align__(16) u16 sK[64 * 64];
  __shared__ __align__(16) u16 sV[64 * 64];   // Vt tile: [d][s_local]
  __shared__ __align__(16) u16 sP[128 * 72];  // padded stride 72 (144B, 16B-aligned rows)
  __shared__ float bt[2048];
  const int tid = threadIdx.x, lane = tid & 63, wave = tid >> 6;
  const int l15 = lane & 15, quad = lane >> 4;
  const int qt = blockIdx.x, bh = blockIdx.y;
  const int h = bh & 15, b = bh >> 4;
  const u16* Qp = Q + bh * 65536 + qt * 8192;
  const u16* Kp = K + bh * 65536;
  const u16* Vp = V + bh * 65536;

#pragma unroll
  for (int r = 0; r < 4; r++)
    gld16(sQ + (r * 256 + wave * 64) * 8, Qp + (r * 256 + wave * 64 + lane) * 8);
  for (int i = tid; i < 2047; i += 256)
    bt[i] = emb[t5_bucket(i - 1023) * 16 + h];

  float mst[2][4], lst[2][4];
  f32x4 oc[2][4];
  const f32x4 vz = {0.f, 0.f, 0.f, 0.f};
#pragma unroll
  for (int mt = 0; mt < 2; mt++) {
#pragma unroll
    for (int r = 0; r < 4; r++) { mst[mt][r] = -1e30f; lst[mt][r] = 0.f; }
#pragma unroll
    for (int nt = 0; nt < 4; nt++) oc[mt][nt] = vz;
  }
  __syncthreads();

  for (int j = 0; j < 16; j++) {
    const u16* Kj = Kp + j * 4096;
#pragma unroll
    for (int r = 0; r < 2; r++)
      gld16(sK + (r * 256 + wave * 64) * 8, Kj + (r * 256 + wave * 64 + lane) * 8);
#pragma unroll
    for (int r = 0; r < 2; r++) {
      int cb = r * 256 + wave * 64;
      int cc = cb + lane;
      gld16(sV + cb * 8, Vp + (cc >> 3) * 1024 + j * 64 + (cc & 7) * 8);
    }
    __syncthreads();

    // scores: S = Q(128x64) . K^T(64x64); wave owns 32 q-rows
    f32x4 sc[2][4];
#pragma unroll
    for (int mt = 0; mt < 2; mt++)
#pragma unroll
      for (int nt = 0; nt < 4; nt++) sc[mt][nt] = vz;
#pragma unroll
    for (int kk = 0; kk < 2; kk++) {
      bf16x8 aq[2], bk[4];
#pragma unroll
      for (int mt = 0; mt < 2; mt++)
        aq[mt] = *(const bf16x8*)(sQ + (wave * 32 + mt * 16 + l15) * 64 + kk * 32 + quad * 8);
#pragma unroll
      for (int nt = 0; nt < 4; nt++)
        bk[nt] = *(const bf16x8*)(sK + (nt * 16 + l15) * 64 + kk * 32 + quad * 8);
#pragma unroll
      for (int mt = 0; mt < 2; mt++)
#pragma unroll
        for (int nt = 0; nt < 4; nt++)
          sc[mt][nt] = MFMA16(aq[mt], bk[nt], sc[mt][nt]);
    }

    // bias + online softmax (fp32)
#pragma unroll
    for (int mt = 0; mt < 2; mt++) {
#pragma unroll
      for (int reg = 0; reg < 4; reg++) {
        int rq = qt * 128 + wave * 32 + mt * 16 + quad * 4 + reg;
        float mx = -1e30f;
#pragma unroll
        for (int nt = 0; nt < 4; nt++) {
          int key = j * 64 + nt * 16 + l15;
          float s = sc[mt][nt][reg] + bt[key - rq + 1023];
          sc[mt][nt][reg] = s;
          mx = fmaxf(mx, s);
        }
#pragma unroll
        for (int d = 1; d < 16; d <<= 1) mx = fmaxf(mx, __shfl_xor(mx, d, 64));
        float mnew = fmaxf(mst[mt][reg], mx);
        float alpha = __expf(mst[mt][reg] - mnew);
        float rs = 0.f;
#pragma unroll
        for (int nt = 0; nt < 4; nt++) {
          float p = __expf(sc[mt][nt][reg] - mnew);
          sc[mt][nt][reg] = p;
          rs += p;
        }
#pragma unroll
        for (int d = 1; d < 16; d <<= 1) rs += __shfl_xor(rs, d, 64);
        lst[mt][reg] = lst[mt][reg] * alpha + rs;
        mst[mt][reg] = mnew;
#pragma unroll
        for (int nt = 0; nt < 4; nt++) oc[mt][nt][reg] *= alpha;
      }
    }

    // P -> LDS (C-layout write, A-layout read; wave-private rows, DS pipe is in-order)
#pragma unroll
    for (int mt = 0; mt < 2; mt++)
#pragma unroll
      for (int reg = 0; reg < 4; reg++)
#pragma unroll
        for (int nt = 0; nt < 4; nt++)
          sP[(wave * 32 + mt * 16 + quad * 4 + reg) * 72 + nt * 16 + l15] = f2bf(sc[mt][nt][reg]);
    asm volatile("s_waitcnt lgkmcnt(0)" ::: "memory");

    // O += P(32x64) . V(64x64)
#pragma unroll
    for (int kk = 0; kk < 2; kk++) {
      bf16x8 ap[2], bv[4];
#pragma unroll
      for (int mt = 0; mt < 2; mt++)
        ap[mt] = *(const bf16x8*)(sP + (wave * 32 + mt * 16 + l15) * 72 + kk * 32 + quad * 8);
#pragma unroll
      for (int nt = 0; nt < 4; nt++)
        bv[nt] = *(const bf16x8*)(sV + (nt * 16 + l15) * 64 + kk * 32 + quad * 8);
#pragma unroll
      for (int mt = 0; mt < 2; mt++)
#pragma unroll
        for (int nt = 0; nt < 4; nt++)
          oc[mt][nt] = MFMA16(ap[mt], bv[nt], oc[mt][nt]);
    }
    __syncthreads();
  }

  // epilogue: ctx[b, s, h*64+d] bf16
#pragma unroll
  for (int mt = 0; mt < 2; mt++)
#pragma unroll
    for (int nt = 0; nt < 4; nt++)
#pragma unroll
      for (int reg = 0; reg < 4; reg++) {
        int rq = wave * 32 + mt * 16 + quad * 4 + reg;
        int s_idx = qt * 128 + rq;
        int d = nt * 16 + l15;
        float v = oc[mt][nt][reg] / lst[mt][reg];
        ctx[b * 1048576 + s_idx * 1024 + h * 64 + d] = f2bf(v);
      }
}

extern "C" void kernel_launch(void* const* d_in, const int* in_sizes, int n_in,
                              void* d_out, int out_size, void* d_ws, size_t ws_size,
                              hipStream_t stream) {
  (void)in_sizes; (void)n_in; (void)out_size; (void)ws_size;
  const float* X   = (const float*)d_in[0];
  const float* Wq  = (const float*)d_in[1];
  const float* Wk  = (const float*)d_in[2];
  const float* Wv  = (const float*)d_in[3];
  const float* Wo  = (const float*)d_in[4];
  const float* emb = (const float*)d_in[5];

  char* ws = (char*)d_ws;
  u16* Xb  = (u16*)(ws);                              // 8 MB: X bf16 [4096][1024]
  u16* Wt  = (u16*)(ws + (8u  << 20));                // 8 MB: Wq^T,Wk^T,Wv^T,Wo^T bf16, 1M each
  u16* Qb  = (u16*)(ws + (16u << 20));                // 8+8+8 MB: Q, K, Vt
  u16* Ctx = (u16*)(ws + (40u << 20));                // 8 MB: attention output bf16

  cvt_x<<<4096, 256, 0, stream>>>((const float4*)X, (ushort4*)Xb);
  wcvt<<<dim3(16, 16, 4), 256, 0, stream>>>(Wq, Wk, Wv, Wo, Wt);
  gemm128<<<dim3(8, 32, 3), 256, 0, stream>>>(Xb, Wt, Qb, -1);
  attn<<<dim3(8, 64), 256, 0, stream>>>(Qb, Qb + 4194304, Qb + 2 * 4194304, emb, Ctx);
  gemm128<<<dim3(8, 32, 1), 256, 0, stream>>>(Ctx, Wt + 3 * 1048576, d_out, 3);
}

// Round 2
// 185.879 us; speedup vs baseline: 1.3596x; 1.3596x over previous
//
#include <hip/hip_runtime.h>

typedef unsigned short u16;
typedef unsigned int u32;
typedef __bf16 bf16x8 __attribute__((ext_vector_type(8)));
typedef float f32x4 __attribute__((ext_vector_type(4)));

#define MFMA16(a, b, c) __builtin_amdgcn_mfma_f32_16x16x32_bf16(a, b, c, 0, 0, 0)
#define LOG2E 1.4426950408889634f

__device__ __forceinline__ u16 f2bf(float f) {
  u32 u = __float_as_uint(f);
  u += 0x7FFFu + ((u >> 16) & 1u);   // RNE to bf16
  return (u16)(u >> 16);
}

// async global->LDS, 16B per lane; lds base wave-uniform, HW writes base + lane*16
__device__ __forceinline__ void gld16(u16* lds, const u16* g) {
  __builtin_amdgcn_global_load_lds((const __attribute__((address_space(1))) void*)g,
                                   (__attribute__((address_space(3))) void*)lds,
                                   16, 0, 0);
}

// Exact integer replication of T5 bucketing (bidirectional, 32 buckets, max_dist 128).
__device__ __forceinline__ int t5_bucket(int rp) {
  int ret = rp > 0 ? 16 : 0;
  int a = rp < 0 ? -rp : rp;
  int b;
  if      (a <  8) b = a;
  else if (a < 12) b = 8;
  else if (a < 16) b = 9;
  else if (a < 23) b = 10;
  else if (a < 32) b = 11;
  else if (a < 46) b = 12;
  else if (a < 64) b = 13;
  else if (a < 91) b = 14;
  else             b = 15;
  return ret + b;
}

// ---------------- fp32 -> bf16 convert of hidden_states ----------------
__global__ __launch_bounds__(256) void cvt_x(const float4* __restrict__ X,
                                             ushort4* __restrict__ Xb) {
  int g = blockIdx.x * 256 + threadIdx.x;
  float4 v = X[g];
  ushort4 o;
  o.x = f2bf(v.x); o.y = f2bf(v.y); o.z = f2bf(v.z); o.w = f2bf(v.w);
  Xb[g] = o;
}

// ---------------- weight convert + transpose: W[k][n] fp32 -> Wt[n][k] bf16 ----------------
__global__ __launch_bounds__(256) void wcvt(const float* __restrict__ w0, const float* __restrict__ w1,
                                            const float* __restrict__ w2, const float* __restrict__ w3,
                                            u16* __restrict__ out) {
  const int z = blockIdx.z;
  const float* W = (z == 0) ? w0 : (z == 1) ? w1 : (z == 2) ? w2 : w3;
  u16* O = out + z * 1048576;
  __shared__ __align__(16) u16 t[64 * 68];
  const int col = threadIdx.x & 63;
  const int rowo = threadIdx.x >> 6;
  const int n0 = blockIdx.x * 64, k0 = blockIdx.y * 64;
#pragma unroll
  for (int r = 0; r < 16; r++) {
    int kl = r * 4 + rowo;
    t[col * 68 + kl] = f2bf(W[(k0 + kl) * 1024 + n0 + col]);
  }
  __syncthreads();
#pragma unroll
  for (int r = 0; r < 16; r++) {
    int nl = r * 4 + rowo;
    O[(n0 + nl) * 1024 + k0 + col] = t[nl * 68 + col];
  }
}

// ---------------- 128x128 bf16 GEMM, C = A[4096x1024] @ Bt[1024x1024]^T ----------------
// modeSel: -1 -> mode = blockIdx.z (0:Q layout scaled by log2e, 1:K layout, 2:Vt layout), 3 -> fp32 out
__global__ __launch_bounds__(256) void gemm128(const u16* __restrict__ A,
                                               const u16* __restrict__ BtBase,
                                               void* __restrict__ outp, int modeSel) {
  __shared__ __align__(16) u16 smem[17408];   // sA(8192) + sB(8192); reused as 128x136 transpose buf
  u16* sA = smem;
  u16* sB = smem + 8192;
  const int tid = threadIdx.x, lane = tid & 63, wave = tid >> 6;
  const int l15 = lane & 15, quad = lane >> 4;
  const int wm = (wave >> 1) * 64, wn = (wave & 1) * 64;
  const int m0 = blockIdx.y * 128, n0 = blockIdx.x * 128;
  const int z = blockIdx.z;
  const int mode = (modeSel < 0) ? z : modeSel;
  const u16* Bt = BtBase + ((modeSel < 0) ? z * 1048576 : 0);

  f32x4 acc[4][4];
  const f32x4 vz = {0.f, 0.f, 0.f, 0.f};
#pragma unroll
  for (int i = 0; i < 4; i++)
#pragma unroll
    for (int j = 0; j < 4; j++) acc[i][j] = vz;

  const int sx = l15 & 7;   // per-lane xor-swizzle key for reads

  for (int kt = 0; kt < 16; kt++) {
    const int ka = kt * 64;
#pragma unroll
    for (int r = 0; r < 4; r++) {
      int cb = r * 256 + wave * 64;
      int cc = cb + lane;
      int row = cc >> 3, c8 = (cc & 7) ^ (cc >> 3 & 7);
      gld16(sA + cb * 8, A  + (m0 + row) * 1024 + ka + c8 * 8);
      gld16(sB + cb * 8, Bt + (n0 + row) * 1024 + ka + c8 * 8);
    }
    __syncthreads();
#pragma unroll
    for (int kk = 0; kk < 2; kk++) {
      bf16x8 af[4], bg[4];
      int g8 = kk * 4 + quad;
#pragma unroll
      for (int mt = 0; mt < 4; mt++)
        af[mt] = *(const bf16x8*)(sA + (wm + mt * 16 + l15) * 64 + (g8 ^ sx) * 8);
#pragma unroll
      for (int nt = 0; nt < 4; nt++)
        bg[nt] = *(const bf16x8*)(sB + (wn + nt * 16 + l15) * 64 + (g8 ^ sx) * 8);
#pragma unroll
      for (int mt = 0; mt < 4; mt++)
#pragma unroll
        for (int nt = 0; nt < 4; nt++)
          acc[mt][nt] = MFMA16(af[mt], bg[nt], acc[mt][nt]);
    }
    __syncthreads();
  }

  if (mode == 3) {
    float* O = (float*)outp;
#pragma unroll
    for (int mt = 0; mt < 4; mt++)
#pragma unroll
      for (int nt = 0; nt < 4; nt++)
#pragma unroll
        for (int reg = 0; reg < 4; reg++) {
          int row = m0 + wm + mt * 16 + quad * 4 + reg;
          int col = n0 + wn + nt * 16 + l15;
          O[row * 1024 + col] = acc[mt][nt][reg];
        }
  } else if (mode == 2) {
    // transpose in LDS (stride 136 u16) then 16B coalesced stores to Vt[b,h,dk,s]
    u16* O = (u16*)outp + z * 4194304;
#pragma unroll
    for (int mt = 0; mt < 4; mt++)
#pragma unroll
      for (int nt = 0; nt < 4; nt++) {
        int col = wn + nt * 16 + l15;           // n-local
        int rowb = wm + mt * 16 + quad * 4;     // m-local, 4 regs contiguous
        uint2 p;
        p.x = (u32)f2bf(acc[mt][nt][0]) | ((u32)f2bf(acc[mt][nt][1]) << 16);
        p.y = (u32)f2bf(acc[mt][nt][2]) | ((u32)f2bf(acc[mt][nt][3]) << 16);
        *(uint2*)(smem + col * 136 + rowb) = p;
      }
    __syncthreads();
    const int b = m0 >> 10, sbase = m0 & 1023;
#pragma unroll
    for (int p = 0; p < 8; p++) {
      int g = p * 256 + tid;
      int col = g >> 4, chunk = g & 15;
      uint4 v = *(const uint4*)(smem + col * 136 + chunk * 8);
      int n = n0 + col, hh = n >> 6, dk = n & 63;
      *(uint4*)(O + ((b * 16 + hh) * 64 + dk) * 1024 + sbase + chunk * 8) = v;
    }
  } else {
    u16* O = (u16*)outp + z * 4194304;
    const float scl = (mode == 0) ? LOG2E : 1.0f;   // pre-scale Q for exp2-softmax
#pragma unroll
    for (int mt = 0; mt < 4; mt++)
#pragma unroll
      for (int nt = 0; nt < 4; nt++)
#pragma unroll
        for (int reg = 0; reg < 4; reg++) {
          int row = m0 + wm + mt * 16 + quad * 4 + reg;   // m = b*1024 + s
          int col = n0 + wn + nt * 16 + l15;              // n = h*64 + dk
          int bb = row >> 10, s = row & 1023, hh = col >> 6, dk = col & 63;
          O[(bb * 16 + hh) * 65536 + s * 64 + dk] = f2bf(acc[mt][nt][reg] * scl);
        }
  }
}

// ---------------- flash attention v2: one block = (b,h) x 64 q-rows ----------------
// S^T formulation: S^T = K.Q^T so P exits MFMA with keys contiguous per lane.
// No online max (scores bounded; Q pre-scaled by log2e, exp2 softmax, bias as MFMA C-init).
__global__ __launch_bounds__(256, 4) void attn(const u16* __restrict__ Q, const u16* __restrict__ K,
                                               const u16* __restrict__ V, const float* __restrict__ emb,
                                               u16* __restrict__ ctx) {
  __shared__ __align__(16) u16 sK[64 * 64];   // [key][dk], dk xor-swizzled
  __shared__ __align__(16) u16 sV[64 * 64];   // V^T tile [d][s], s xor-swizzled
  __shared__ __align__(16) u16 sP[64 * 72];   // P [qrow][key], stride 72
  __shared__ float bt[1088];                  // bias * log2e, idx = rp + qt*64 + 63
  const int tid = threadIdx.x, lane = tid & 63, wave = tid >> 6;
  const int l15 = lane & 15, quad = lane >> 4;
  const int bh = blockIdx.x, qt = blockIdx.y;   // bh-major -> same-head blocks share XCD L2
  const int h = bh & 15, b = bh >> 4;
  const u16* Qp = Q + bh * 65536 + qt * 4096;
  const u16* Kp = K + bh * 65536;
  const u16* Vp = V + bh * 65536;
  const int sx = l15 & 7;

  // Q fragment in registers (wave-private 16 q-rows); doubles as B-operand of S^T
  bf16x8 aq[2];
#pragma unroll
  for (int kk = 0; kk < 2; kk++)
    aq[kk] = *(const bf16x8*)(Qp + (wave * 16 + l15) * 64 + kk * 32 + quad * 8);

  for (int i = tid; i < 1088; i += 256) {
    int rp = i - qt * 64 - 63;
    bt[i] = emb[t5_bucket(rp) * 16 + h] * LOG2E;
  }

  float lsum = 0.f;
  f32x4 oc[4];
  const f32x4 vz = {0.f, 0.f, 0.f, 0.f};
#pragma unroll
  for (int nt = 0; nt < 4; nt++) oc[nt] = vz;

  __syncthreads();   // bt ready

#pragma unroll 1
  for (int j = 0; j < 16; j++) {
    const u16* Kj = Kp + j * 4096;
#pragma unroll
    for (int r = 0; r < 2; r++) {
      int cb = r * 256 + wave * 64;
      int cc = cb + lane;
      int row = cc >> 3, c8 = (cc & 7) ^ (row & 7);
      gld16(sK + cb * 8, Kj + row * 64 + c8 * 8);
      gld16(sV + cb * 8, Vp + row * 1024 + j * 64 + c8 * 8);
    }
    __syncthreads();   // staged tiles visible (implicit vmcnt drain)

    // S^T = K . Q^T + bias  (C-layout: lane holds key = mt*16+quad*4+reg, qrow = l15)
    f32x4 sc[4];
    const int bbase = j * 64 + 63 + quad * 4 - wave * 16 - l15;
#pragma unroll
    for (int mt = 0; mt < 4; mt++)
#pragma unroll
      for (int reg = 0; reg < 4; reg++)
        sc[mt][reg] = bt[bbase + mt * 16 + reg];
#pragma unroll
    for (int kk = 0; kk < 2; kk++) {
      bf16x8 ak[4];
      int g8 = kk * 4 + quad;
#pragma unroll
      for (int mt = 0; mt < 4; mt++)
        ak[mt] = *(const bf16x8*)(sK + (mt * 16 + l15) * 64 + (g8 ^ sx) * 8);
#pragma unroll
      for (int mt = 0; mt < 4; mt++)
        sc[mt] = MFMA16(ak[mt], aq[kk], sc[mt]);
    }

    // softmax without max-tracking: p = exp2(score'), per-lane partial row sum
    const int prow = wave * 16 + l15;
#pragma unroll
    for (int mt = 0; mt < 4; mt++) {
#pragma unroll
      for (int reg = 0; reg < 4; reg++) {
        float p = __builtin_amdgcn_exp2f(sc[mt][reg]);
        sc[mt][reg] = p;
        lsum += p;
      }
      uint2 pk;
      pk.x = (u32)f2bf(sc[mt][0]) | ((u32)f2bf(sc[mt][1]) << 16);
      pk.y = (u32)f2bf(sc[mt][2]) | ((u32)f2bf(sc[mt][3]) << 16);
      *(uint2*)(sP + prow * 72 + mt * 16 + quad * 4) = pk;   // P[qrow][key] b64 write
    }
    asm volatile("s_waitcnt lgkmcnt(0)" ::: "memory");   // wave-private P write->read

    // O += P . V   (A = P rows, B = V from V^T tile)
#pragma unroll
    for (int kk = 0; kk < 2; kk++) {
      bf16x8 ap = *(const bf16x8*)(sP + prow * 72 + kk * 32 + quad * 8);
      int g8 = kk * 4 + quad;
#pragma unroll
      for (int nt = 0; nt < 4; nt++) {
        bf16x8 bv = *(const bf16x8*)(sV + (nt * 16 + l15) * 64 + (g8 ^ sx) * 8);
        oc[nt] = MFMA16(ap, bv, oc[nt]);
      }
    }
    __syncthreads();   // protect sK/sV before next stage
  }

  // row-sum: lanes sharing qrow (same l15 across quads) hold disjoint key partials
  lsum += __shfl_xor(lsum, 16, 64);
  lsum += __shfl_xor(lsum, 32, 64);
  float linv[4];
#pragma unroll
  for (int reg = 0; reg < 4; reg++)
    linv[reg] = __builtin_amdgcn_rcpf(__shfl(lsum, quad * 4 + reg, 64));

  u16* cbase = ctx + b * 1048576 + (qt * 64 + wave * 16) * 1024 + h * 64;
#pragma unroll
  for (int nt = 0; nt < 4; nt++)
#pragma unroll
    for (int reg = 0; reg < 4; reg++)
      cbase[(quad * 4 + reg) * 1024 + nt * 16 + l15] = f2bf(oc[nt][reg] * linv[reg]);
}

extern "C" void kernel_launch(void* const* d_in, const int* in_sizes, int n_in,
                              void* d_out, int out_size, void* d_ws, size_t ws_size,
                              hipStream_t stream) {
  (void)in_sizes; (void)n_in; (void)out_size; (void)ws_size;
  const float* X   = (const float*)d_in[0];
  const float* Wq  = (const float*)d_in[1];
  const float* Wk  = (const float*)d_in[2];
  const float* Wv  = (const float*)d_in[3];
  const float* Wo  = (const float*)d_in[4];
  const float* emb = (const float*)d_in[5];

  char* ws = (char*)d_ws;
  u16* Xb  = (u16*)(ws);                              // 8 MB: X bf16 [4096][1024]
  u16* Wt  = (u16*)(ws + (8u  << 20));                // 8 MB: Wq^T,Wk^T,Wv^T,Wo^T bf16
  u16* Qb  = (u16*)(ws + (16u << 20));                // 8+8+8 MB: Q(log2e-scaled), K, Vt
  u16* Ctx = (u16*)(ws + (40u << 20));                // 8 MB: attention output bf16

  cvt_x<<<4096, 256, 0, stream>>>((const float4*)X, (ushort4*)Xb);
  wcvt<<<dim3(16, 16, 4), 256, 0, stream>>>(Wq, Wk, Wv, Wo, Wt);
  gemm128<<<dim3(8, 32, 3), 256, 0, stream>>>(Xb, Wt, Qb, -1);
  attn<<<dim3(64, 16), 256, 0, stream>>>(Qb, Qb + 4194304, Qb + 2 * 4194304, emb, Ctx);
  gemm128<<<dim3(8, 32, 1), 256, 0, stream>>>(Ctx, Wt + 3 * 1048576, d_out, 3);
}

// Round 3
// 179.490 us; speedup vs baseline: 1.4080x; 1.0356x over previous
//
#include <hip/hip_runtime.h>

typedef unsigned short u16;
typedef unsigned int u32;
typedef __bf16 bf16x8 __attribute__((ext_vector_type(8)));
typedef float f32x4 __attribute__((ext_vector_type(4)));

#define MFMA16(a, b, c) __builtin_amdgcn_mfma_f32_16x16x32_bf16(a, b, c, 0, 0, 0)
#define LOG2E 1.4426950408889634f

__device__ __forceinline__ u16 f2bf(float f) {
  u32 u = __float_as_uint(f);
  u += 0x7FFFu + ((u >> 16) & 1u);   // RNE to bf16
  return (u16)(u >> 16);
}

__device__ __forceinline__ void gld16(u16* lds, const u16* g) {
  __builtin_amdgcn_global_load_lds((const __attribute__((address_space(1))) void*)g,
                                   (__attribute__((address_space(3))) void*)lds,
                                   16, 0, 0);
}

// Exact integer replication of T5 bucketing (bidirectional, 32 buckets, max_dist 128).
__device__ __forceinline__ int t5_bucket(int rp) {
  int ret = rp > 0 ? 16 : 0;
  int a = rp < 0 ? -rp : rp;
  int b;
  if      (a <  8) b = a;
  else if (a < 12) b = 8;
  else if (a < 16) b = 9;
  else if (a < 23) b = 10;
  else if (a < 32) b = 11;
  else if (a < 46) b = 12;
  else if (a < 64) b = 13;
  else if (a < 91) b = 14;
  else             b = 15;
  return ret + b;
}

// ---------------- fused prep: X fp32->bf16 (blocks 0..4095) + weight cvt/transpose (4096..5119) ----
__global__ __launch_bounds__(256) void prep(const float4* __restrict__ X, ushort4* __restrict__ Xb,
                                            const float* __restrict__ w0, const float* __restrict__ w1,
                                            const float* __restrict__ w2, const float* __restrict__ w3,
                                            u16* __restrict__ out) {
  int bid = blockIdx.x;
  if (bid < 4096) {
    int g = bid * 256 + threadIdx.x;
    float4 v = X[g];
    ushort4 o;
    o.x = f2bf(v.x); o.y = f2bf(v.y); o.z = f2bf(v.z); o.w = f2bf(v.w);
    Xb[g] = o;
    return;
  }
  bid -= 4096;
  const int z = bid >> 8, t = bid & 255;
  const float* W = (z == 0) ? w0 : (z == 1) ? w1 : (z == 2) ? w2 : w3;
  u16* O = out + z * 1048576;
  __shared__ __align__(16) u16 tb[64 * 68];
  const int col = threadIdx.x & 63;
  const int rowo = threadIdx.x >> 6;
  const int n0 = (t & 15) * 64, k0 = (t >> 4) * 64;
#pragma unroll
  for (int r = 0; r < 16; r++) {
    int kl = r * 4 + rowo;
    tb[col * 68 + kl] = f2bf(W[(k0 + kl) * 1024 + n0 + col]);
  }
  __syncthreads();
#pragma unroll
  for (int r = 0; r < 16; r++) {
    int nl = r * 4 + rowo;
    O[(n0 + nl) * 1024 + k0 + col] = tb[nl * 68 + col];
  }
}

// ---------------- QKV GEMM: 128x128 tiles, z in {0:Q(scaled),1:K,2:Vt} ----------------
// XCD-aware decode: xcd = id%8 owns 8 m-panels x 12 (n,z)-panels (~5MB L2 working set)
__global__ __launch_bounds__(256) void gemm128(const u16* __restrict__ A,
                                               const u16* __restrict__ BtBase,
                                               u16* __restrict__ outp) {
  __shared__ __align__(16) u16 smem[17408];
  u16* sA = smem;
  u16* sB = smem + 8192;
  const int tid = threadIdx.x, lane = tid & 63, wave = tid >> 6;
  const int l15 = lane & 15, quad = lane >> 4;
  const int wm = (wave >> 1) * 64, wn = (wave & 1) * 64;

  const int id = blockIdx.x + blockIdx.y * 24;
  const int xcd = id & 7, jj = id >> 3;
  const int nz = (jj % 12) + (xcd & 1) * 12;
  const int ymb = (jj / 12) + (xcd >> 1) * 8;
  const int n = nz / 3, z = nz % 3;
  const int m0 = ymb * 128, n0 = n * 128;
  const u16* Bt = BtBase + z * 1048576;

  f32x4 acc[4][4];
  const f32x4 vz = {0.f, 0.f, 0.f, 0.f};
#pragma unroll
  for (int i = 0; i < 4; i++)
#pragma unroll
    for (int j = 0; j < 4; j++) acc[i][j] = vz;

  const int sx = l15 & 7;

  for (int kt = 0; kt < 16; kt++) {
    const int ka = kt * 64;
#pragma unroll
    for (int r = 0; r < 4; r++) {
      int cb = r * 256 + wave * 64;
      int cc = cb + lane;
      int row = cc >> 3, c8 = (cc & 7) ^ (row & 7);
      gld16(sA + cb * 8, A  + (m0 + row) * 1024 + ka + c8 * 8);
      gld16(sB + cb * 8, Bt + (n0 + row) * 1024 + ka + c8 * 8);
    }
    __syncthreads();
#pragma unroll
    for (int kk = 0; kk < 2; kk++) {
      bf16x8 af[4], bg[4];
      int g8 = kk * 4 + quad;
#pragma unroll
      for (int mt = 0; mt < 4; mt++)
        af[mt] = *(const bf16x8*)(sA + (wm + mt * 16 + l15) * 64 + (g8 ^ sx) * 8);
#pragma unroll
      for (int nt = 0; nt < 4; nt++)
        bg[nt] = *(const bf16x8*)(sB + (wn + nt * 16 + l15) * 64 + (g8 ^ sx) * 8);
#pragma unroll
      for (int mt = 0; mt < 4; mt++)
#pragma unroll
        for (int nt = 0; nt < 4; nt++)
          acc[mt][nt] = MFMA16(af[mt], bg[nt], acc[mt][nt]);
    }
    __syncthreads();
  }

  if (z == 2) {
    // transpose in LDS (stride 136 u16) then 16B coalesced stores to Vt[b,h,dk,s]
    u16* O = outp + z * 4194304;
#pragma unroll
    for (int mt = 0; mt < 4; mt++)
#pragma unroll
      for (int nt = 0; nt < 4; nt++) {
        int col = wn + nt * 16 + l15;
        int rowb = wm + mt * 16 + quad * 4;
        uint2 p;
        p.x = (u32)f2bf(acc[mt][nt][0]) | ((u32)f2bf(acc[mt][nt][1]) << 16);
        p.y = (u32)f2bf(acc[mt][nt][2]) | ((u32)f2bf(acc[mt][nt][3]) << 16);
        *(uint2*)(smem + col * 136 + rowb) = p;
      }
    __syncthreads();
    const int b = m0 >> 10, sbase = m0 & 1023;
#pragma unroll
    for (int p = 0; p < 8; p++) {
      int g = p * 256 + tid;
      int col = g >> 4, chunk = g & 15;
      uint4 v = *(const uint4*)(smem + col * 136 + chunk * 8);
      int nn = n0 + col, hh = nn >> 6, dk = nn & 63;
      *(uint4*)(O + ((b * 16 + hh) * 64 + dk) * 1024 + sbase + chunk * 8) = v;
    }
  } else {
    u16* O = outp + z * 4194304;
    const float scl = (z == 0) ? LOG2E : 1.0f;   // pre-scale Q for exp2-softmax
#pragma unroll
    for (int mt = 0; mt < 4; mt++)
#pragma unroll
      for (int nt = 0; nt < 4; nt++)
#pragma unroll
        for (int reg = 0; reg < 4; reg++) {
          int row = m0 + wm + mt * 16 + quad * 4 + reg;
          int col = n0 + wn + nt * 16 + l15;
          int bb = row >> 10, s = row & 1023, hh = col >> 6, dk = col & 63;
          O[(bb * 16 + hh) * 65536 + s * 64 + dk] = f2bf(acc[mt][nt][reg] * scl);
        }
  }
}

// ---------------- flash attention v3: block = (b,h) x 128 q-rows; wave = 32q x 64keys ----------------
__global__ __launch_bounds__(256) void attn(const u16* __restrict__ Q, const u16* __restrict__ K,
                                            const u16* __restrict__ V, const float* __restrict__ emb,
                                            u16* __restrict__ ctx) {
  __shared__ __align__(16) u16 sK[64 * 64];
  __shared__ __align__(16) u16 sV[64 * 64];     // V^T tile [d][s_local]
  __shared__ __align__(16) u16 sP[128 * 72];    // P [qrow][key], stride 72 (144B, 16B aligned)
  __shared__ __align__(16) float4 bt4[1156];    // replicated bias*log2e: bt4[i][c] = bias(i-127-qt*128+c)
  const int tid = threadIdx.x, lane = tid & 63, wave = tid >> 6;
  const int l15 = lane & 15, quad = lane >> 4;
  const int bh = blockIdx.x, qt = blockIdx.y;   // bh-major: 8 qt-siblings share XCD L2 for K/V
  const int h = bh & 15, b = bh >> 4;
  const u16* Qp = Q + bh * 65536 + qt * 8192;
  const u16* Kp = K + bh * 65536;
  const u16* Vp = V + bh * 65536;
  const int sx = l15 & 7;

  // Q fragments in registers: wave owns 32 q-rows (2 subtiles), B-operand of S^T
  bf16x8 aq[2][2];
#pragma unroll
  for (int u = 0; u < 2; u++)
#pragma unroll
    for (int kk = 0; kk < 2; kk++)
      aq[u][kk] = *(const bf16x8*)(Qp + (wave * 32 + u * 16 + l15) * 64 + kk * 32 + quad * 8);

  for (int i = tid; i < 1156; i += 256) {
    int rp0 = i - 127 - qt * 128;
    float4 v;
    v.x = emb[t5_bucket(rp0)     * 16 + h] * LOG2E;
    v.y = emb[t5_bucket(rp0 + 1) * 16 + h] * LOG2E;
    v.z = emb[t5_bucket(rp0 + 2) * 16 + h] * LOG2E;
    v.w = emb[t5_bucket(rp0 + 3) * 16 + h] * LOG2E;
    bt4[i] = v;
  }
  const float bias_pos = emb[31 * 16 + h] * LOG2E;  // rp >= 91
  const float bias_neg = emb[15 * 16 + h] * LOG2E;  // rp <= -91

  float lsum[2] = {0.f, 0.f};
  f32x4 oc[2][4];
  const f32x4 vzero = {0.f, 0.f, 0.f, 0.f};
#pragma unroll
  for (int u = 0; u < 2; u++)
#pragma unroll
    for (int nt = 0; nt < 4; nt++) oc[u][nt] = vzero;

  __syncthreads();   // bt4 ready

#pragma unroll 1
  for (int j = 0; j < 16; j++) {
    const u16* Kj = Kp + j * 4096;
#pragma unroll
    for (int r = 0; r < 2; r++) {
      int cb = r * 256 + wave * 64;
      int cc = cb + lane;
      int row = cc >> 3, c8 = (cc & 7) ^ (row & 7);
      gld16(sK + cb * 8, Kj + row * 64 + c8 * 8);
      gld16(sV + cb * 8, Vp + row * 1024 + j * 64 + c8 * 8);
    }
    __syncthreads();

    // S^T = K.Q^T + bias: C tiles [mt=key/16][u=qrow/16]; lane: key=mt*16+quad*4+reg, q=u*16+l15
    f32x4 sc[4][2];
    const int rp_min = j * 64 - qt * 128 - 127;
    const int rp_max = j * 64 + 63 - qt * 128;
    if (rp_min >= 91) {
#pragma unroll
      for (int mt = 0; mt < 4; mt++)
#pragma unroll
        for (int u = 0; u < 2; u++) { sc[mt][u][0] = bias_pos; sc[mt][u][1] = bias_pos; sc[mt][u][2] = bias_pos; sc[mt][u][3] = bias_pos; }
    } else if (rp_max <= -91) {
#pragma unroll
      for (int mt = 0; mt < 4; mt++)
#pragma unroll
        for (int u = 0; u < 2; u++) { sc[mt][u][0] = bias_neg; sc[mt][u][1] = bias_neg; sc[mt][u][2] = bias_neg; sc[mt][u][3] = bias_neg; }
    } else {
#pragma unroll
      for (int mt = 0; mt < 4; mt++)
#pragma unroll
        for (int u = 0; u < 2; u++) {
          int idx = j * 64 + mt * 16 + quad * 4 - wave * 32 - u * 16 - l15 + 127;
          float4 bv4 = bt4[idx];
          sc[mt][u][0] = bv4.x; sc[mt][u][1] = bv4.y; sc[mt][u][2] = bv4.z; sc[mt][u][3] = bv4.w;
        }
    }
#pragma unroll
    for (int kk = 0; kk < 2; kk++) {
      bf16x8 ak[4];
      int g8 = kk * 4 + quad;
#pragma unroll
      for (int mt = 0; mt < 4; mt++)
        ak[mt] = *(const bf16x8*)(sK + (mt * 16 + l15) * 64 + (g8 ^ sx) * 8);
#pragma unroll
      for (int mt = 0; mt < 4; mt++)
#pragma unroll
        for (int u = 0; u < 2; u++)
          sc[mt][u] = MFMA16(ak[mt], aq[u][kk], sc[mt][u]);
    }

    // softmax (no max-tracking) + P -> LDS in A-layout rows
#pragma unroll
    for (int u = 0; u < 2; u++) {
      const int prow = wave * 32 + u * 16 + l15;
#pragma unroll
      for (int mt = 0; mt < 4; mt++) {
        float p0 = __builtin_amdgcn_exp2f(sc[mt][u][0]);
        float p1 = __builtin_amdgcn_exp2f(sc[mt][u][1]);
        float p2 = __builtin_amdgcn_exp2f(sc[mt][u][2]);
        float p3 = __builtin_amdgcn_exp2f(sc[mt][u][3]);
        lsum[u] += (p0 + p1) + (p2 + p3);
        uint2 pk;
        pk.x = (u32)f2bf(p0) | ((u32)f2bf(p1) << 16);
        pk.y = (u32)f2bf(p2) | ((u32)f2bf(p3) << 16);
        *(uint2*)(sP + prow * 72 + mt * 16 + quad * 4) = pk;
      }
    }
    asm volatile("s_waitcnt lgkmcnt(0)" ::: "memory");   // wave-private P write->read

    // O += P.V
#pragma unroll
    for (int kk = 0; kk < 2; kk++) {
      bf16x8 ap[2];
      int g8 = kk * 4 + quad;
#pragma unroll
      for (int u = 0; u < 2; u++)
        ap[u] = *(const bf16x8*)(sP + (wave * 32 + u * 16 + l15) * 72 + kk * 32 + quad * 8);
#pragma unroll
      for (int nt = 0; nt < 4; nt++) {
        bf16x8 bv = *(const bf16x8*)(sV + (nt * 16 + l15) * 64 + (g8 ^ sx) * 8);
#pragma unroll
        for (int u = 0; u < 2; u++)
          oc[u][nt] = MFMA16(ap[u], bv, oc[u][nt]);
      }
    }
    __syncthreads();
  }

  // row sums: per-lane partials cover keys {quad*4..+3} x mt; reduce across quads
#pragma unroll
  for (int u = 0; u < 2; u++) {
    lsum[u] += __shfl_xor(lsum[u], 16, 64);
    lsum[u] += __shfl_xor(lsum[u], 32, 64);
  }
  float linv[2][4];
#pragma unroll
  for (int u = 0; u < 2; u++)
#pragma unroll
    for (int reg = 0; reg < 4; reg++)
      linv[u][reg] = __builtin_amdgcn_rcpf(__shfl(lsum[u], quad * 4 + reg, 64));

  u16* cb2 = ctx + b * 1048576 + (qt * 128 + wave * 32) * 1024 + h * 64;
#pragma unroll
  for (int u = 0; u < 2; u++)
#pragma unroll
    for (int nt = 0; nt < 4; nt++)
#pragma unroll
      for (int reg = 0; reg < 4; reg++)
        cb2[(u * 16 + quad * 4 + reg) * 1024 + nt * 16 + l15] = f2bf(oc[u][nt][reg] * linv[u][reg]);
}

// ---------------- out-proj GEMM: 128m x 64n tiles, fp32 out ----------------
__global__ __launch_bounds__(256) void gemm_o(const u16* __restrict__ A,
                                              const u16* __restrict__ Bt,
                                              float* __restrict__ O) {
  __shared__ __align__(16) u16 sA[128 * 64];
  __shared__ __align__(16) u16 sB[64 * 64];
  const int tid = threadIdx.x, lane = tid & 63, wave = tid >> 6;
  const int l15 = lane & 15, quad = lane >> 4;
  const int wm = (wave >> 1) * 64, wn = (wave & 1) * 32;
  const int m0 = blockIdx.x * 128, n0 = blockIdx.y * 64;   // x=m: XCD owns 4 m-panels (A 1MB + B 2MB in L2)

  f32x4 acc[4][2];
  const f32x4 vz = {0.f, 0.f, 0.f, 0.f};
#pragma unroll
  for (int i = 0; i < 4; i++) { acc[i][0] = vz; acc[i][1] = vz; }

  const int sx = l15 & 7;

  for (int kt = 0; kt < 16; kt++) {
    const int ka = kt * 64;
#pragma unroll
    for (int r = 0; r < 4; r++) {
      int cb = r * 256 + wave * 64;
      int cc = cb + lane;
      int row = cc >> 3, c8 = (cc & 7) ^ (row & 7);
      gld16(sA + cb * 8, A + (m0 + row) * 1024 + ka + c8 * 8);
    }
#pragma unroll
    for (int r = 0; r < 2; r++) {
      int cb = r * 256 + wave * 64;
      int cc = cb + lane;
      int row = cc >> 3, c8 = (cc & 7) ^ (row & 7);
      gld16(sB + cb * 8, Bt + (n0 + row) * 1024 + ka + c8 * 8);
    }
    __syncthreads();
#pragma unroll
    for (int kk = 0; kk < 2; kk++) {
      bf16x8 af[4], bg[2];
      int g8 = kk * 4 + quad;
#pragma unroll
      for (int mt = 0; mt < 4; mt++)
        af[mt] = *(const bf16x8*)(sA + (wm + mt * 16 + l15) * 64 + (g8 ^ sx) * 8);
#pragma unroll
      for (int nt = 0; nt < 2; nt++)
        bg[nt] = *(const bf16x8*)(sB + (wn + nt * 16 + l15) * 64 + (g8 ^ sx) * 8);
#pragma unroll
      for (int mt = 0; mt < 4; mt++)
#pragma unroll
        for (int nt = 0; nt < 2; nt++)
          acc[mt][nt] = MFMA16(af[mt], bg[nt], acc[mt][nt]);
    }
    __syncthreads();
  }

#pragma unroll
  for (int mt = 0; mt < 4; mt++)
#pragma unroll
    for (int nt = 0; nt < 2; nt++)
#pragma unroll
      for (int reg = 0; reg < 4; reg++) {
        int row = m0 + wm + mt * 16 + quad * 4 + reg;
        int col = n0 + wn + nt * 16 + l15;
        O[row * 1024 + col] = acc[mt][nt][reg];
      }
}

extern "C" void kernel_launch(void* const* d_in, const int* in_sizes, int n_in,
                              void* d_out, int out_size, void* d_ws, size_t ws_size,
                              hipStream_t stream) {
  (void)in_sizes; (void)n_in; (void)out_size; (void)ws_size;
  const float* X   = (const float*)d_in[0];
  const float* Wq  = (const float*)d_in[1];
  const float* Wk  = (const float*)d_in[2];
  const float* Wv  = (const float*)d_in[3];
  const float* Wo  = (const float*)d_in[4];
  const float* emb = (const float*)d_in[5];

  char* ws = (char*)d_ws;
  u16* Xb  = (u16*)(ws);                              // 8 MB: X bf16 [4096][1024]
  u16* Wt  = (u16*)(ws + (8u  << 20));                // 8 MB: Wq^T,Wk^T,Wv^T,Wo^T bf16
  u16* Qb  = (u16*)(ws + (16u << 20));                // 8+8+8 MB: Q(log2e-scaled), K, Vt
  u16* Ctx = (u16*)(ws + (40u << 20));                // 8 MB: attention output bf16

  prep<<<5120, 256, 0, stream>>>((const float4*)X, (ushort4*)Xb, Wq, Wk, Wv, Wo, Wt);
  gemm128<<<dim3(24, 32), 256, 0, stream>>>(Xb, Wt, Qb);
  attn<<<dim3(64, 8), 256, 0, stream>>>(Qb, Qb + 4194304, Qb + 2 * 4194304, emb, Ctx);
  gemm_o<<<dim3(32, 16), 256, 0, stream>>>(Ctx, Wt + 3 * 1048576, (float*)d_out);
}

// Round 4
// 173.164 us; speedup vs baseline: 1.4594x; 1.0365x over previous
//
#include <hip/hip_runtime.h>

typedef unsigned short u16;
typedef unsigned int u32;
typedef __bf16 bf16x8 __attribute__((ext_vector_type(8)));
typedef float f32x4 __attribute__((ext_vector_type(4)));

#define MFMA16(a, b, c) __builtin_amdgcn_mfma_f32_16x16x32_bf16(a, b, c, 0, 0, 0)
#define LOG2E 1.4426950408889634f

__device__ __forceinline__ u16 f2bf(float f) {
  u32 u = __float_as_uint(f);
  u += 0x7FFFu + ((u >> 16) & 1u);   // RNE to bf16
  return (u16)(u >> 16);
}

__device__ __forceinline__ void gld16(u16* lds, const u16* g) {
  __builtin_amdgcn_global_load_lds((const __attribute__((address_space(1))) void*)g,
                                   (__attribute__((address_space(3))) void*)lds,
                                   16, 0, 0);
}

// Exact integer replication of T5 bucketing (bidirectional, 32 buckets, max_dist 128).
__device__ __forceinline__ int t5_bucket(int rp) {
  int ret = rp > 0 ? 16 : 0;
  int a = rp < 0 ? -rp : rp;
  int b;
  if      (a <  8) b = a;
  else if (a < 12) b = 8;
  else if (a < 16) b = 9;
  else if (a < 23) b = 10;
  else if (a < 32) b = 11;
  else if (a < 46) b = 12;
  else if (a < 64) b = 13;
  else if (a < 91) b = 14;
  else             b = 15;
  return ret + b;
}

// ---------------- fused prep, grid 1024: blocks 0..511 X cvt (grid-stride), 512..1023 W cvt ----
__global__ __launch_bounds__(256) void prep(const float4* __restrict__ X, ushort4* __restrict__ Xb,
                                            const float* __restrict__ w0, const float* __restrict__ w1,
                                            const float* __restrict__ w2, const float* __restrict__ w3,
                                            u16* __restrict__ out) {
  int bid = blockIdx.x;
  if (bid < 512) {
#pragma unroll
    for (int i = 0; i < 8; i++) {
      int g = bid * 2048 + i * 256 + threadIdx.x;
      float4 v = X[g];
      ushort4 o;
      o.x = f2bf(v.x); o.y = f2bf(v.y); o.z = f2bf(v.z); o.w = f2bf(v.w);
      Xb[g] = o;
    }
    return;
  }
  bid -= 512;
  __shared__ __align__(16) u16 tb[64 * 68];
  const int col = threadIdx.x & 63;
  const int rowo = threadIdx.x >> 6;
#pragma unroll 1
  for (int t2 = 0; t2 < 2; t2++) {
    const int tile = bid * 2 + t2;
    const int z = tile >> 8, t = tile & 255;
    const float* W = (z == 0) ? w0 : (z == 1) ? w1 : (z == 2) ? w2 : w3;
    u16* O = out + z * 1048576;
    const int n0 = (t & 15) * 64, k0 = (t >> 4) * 64;
#pragma unroll
    for (int r = 0; r < 16; r++) {
      int kl = r * 4 + rowo;
      tb[col * 68 + kl] = f2bf(W[(k0 + kl) * 1024 + n0 + col]);
    }
    __syncthreads();
#pragma unroll
    for (int r = 0; r < 16; r++) {
      int nl = r * 4 + rowo;
      O[(n0 + nl) * 1024 + k0 + col] = tb[nl * 68 + col];
    }
    __syncthreads();
  }
}

// ---------------- QKV GEMM: 128x128 tiles, z in {0:Q(scaled),1:K,2:Vt} ----------------
// XCD-aware decode: xcd = id%8 owns 8 m-panels x 12 (n,z)-panels (~5MB L2 working set)
__global__ __launch_bounds__(256) void gemm128(const u16* __restrict__ A,
                                               const u16* __restrict__ BtBase,
                                               u16* __restrict__ outp) {
  __shared__ __align__(16) u16 smem[18432];   // sA(8192)+sB(8192) u16; epilogue retile 128x144
  u16* sA = smem;
  u16* sB = smem + 8192;
  const int tid = threadIdx.x, lane = tid & 63, wave = tid >> 6;
  const int l15 = lane & 15, quad = lane >> 4;
  const int wm = (wave >> 1) * 64, wn = (wave & 1) * 64;

  const int id = blockIdx.x + blockIdx.y * 24;
  const int xcd = id & 7, jj = id >> 3;
  const int nz = (jj % 12) + (xcd & 1) * 12;
  const int ymb = (jj / 12) + (xcd >> 1) * 8;
  const int n = nz / 3, z = nz % 3;
  const int m0 = ymb * 128, n0 = n * 128;
  const u16* Bt = BtBase + z * 1048576;

  f32x4 acc[4][4];
  const f32x4 vz = {0.f, 0.f, 0.f, 0.f};
#pragma unroll
  for (int i = 0; i < 4; i++)
#pragma unroll
    for (int j = 0; j < 4; j++) acc[i][j] = vz;

  const int sx = l15 & 7;

  for (int kt = 0; kt < 16; kt++) {
    const int ka = kt * 64;
#pragma unroll
    for (int r = 0; r < 4; r++) {
      int cb = r * 256 + wave * 64;
      int cc = cb + lane;
      int row = cc >> 3, c8 = (cc & 7) ^ (row & 7);
      gld16(sA + cb * 8, A  + (m0 + row) * 1024 + ka + c8 * 8);
      gld16(sB + cb * 8, Bt + (n0 + row) * 1024 + ka + c8 * 8);
    }
    __syncthreads();
#pragma unroll
    for (int kk = 0; kk < 2; kk++) {
      bf16x8 af[4], bg[4];
      int g8 = kk * 4 + quad;
#pragma unroll
      for (int mt = 0; mt < 4; mt++)
        af[mt] = *(const bf16x8*)(sA + (wm + mt * 16 + l15) * 64 + (g8 ^ sx) * 8);
#pragma unroll
      for (int nt = 0; nt < 4; nt++)
        bg[nt] = *(const bf16x8*)(sB + (wn + nt * 16 + l15) * 64 + (g8 ^ sx) * 8);
#pragma unroll
      for (int mt = 0; mt < 4; mt++)
#pragma unroll
        for (int nt = 0; nt < 4; nt++)
          acc[mt][nt] = MFMA16(af[mt], bg[nt], acc[mt][nt]);
    }
    __syncthreads();
  }

  if (z == 2) {
    // transpose in LDS (col-major stride 136) then 16B coalesced stores to Vt[b,h,dk,s]
    u16* O = outp + z * 4194304;
#pragma unroll
    for (int mt = 0; mt < 4; mt++)
#pragma unroll
      for (int nt = 0; nt < 4; nt++) {
        int col = wn + nt * 16 + l15;
        int rowb = wm + mt * 16 + quad * 4;
        uint2 p;
        p.x = (u32)f2bf(acc[mt][nt][0]) | ((u32)f2bf(acc[mt][nt][1]) << 16);
        p.y = (u32)f2bf(acc[mt][nt][2]) | ((u32)f2bf(acc[mt][nt][3]) << 16);
        *(uint2*)(smem + col * 136 + rowb) = p;
      }
    __syncthreads();
    const int b = m0 >> 10, sbase = m0 & 1023;
#pragma unroll
    for (int p = 0; p < 8; p++) {
      int g = p * 256 + tid;
      int col = g >> 4, chunk = g & 15;
      uint4 v = *(const uint4*)(smem + col * 136 + chunk * 8);
      int nn = n0 + col, hh = nn >> 6, dk = nn & 63;
      *(uint4*)(O + ((b * 16 + hh) * 64 + dk) * 1024 + sbase + chunk * 8) = v;
    }
  } else {
    // retile [m][n] in LDS (stride 144: conflict-free across quads) then 16B stores
    u16* O = outp + z * 4194304;
    const float scl = (z == 0) ? LOG2E : 1.0f;   // pre-scale Q for exp2-softmax
#pragma unroll
    for (int mt = 0; mt < 4; mt++)
#pragma unroll
      for (int nt = 0; nt < 4; nt++) {
        int rowb = wm + mt * 16 + quad * 4;
        int colb = wn + nt * 16 + l15;
#pragma unroll
        for (int reg = 0; reg < 4; reg++)
          smem[(rowb + reg) * 144 + colb] = f2bf(acc[mt][nt][reg] * scl);
      }
    __syncthreads();
    const int b = m0 >> 10, sbase = m0 & 1023;
#pragma unroll
    for (int p = 0; p < 8; p++) {
      int g = p * 256 + tid;
      int ml = g >> 4, c = g & 15;
      uint4 v = *(const uint4*)(smem + ml * 144 + c * 8);
      int nn = n0 + c * 8, hh = nn >> 6, dk = nn & 63;
      *(uint4*)(O + (b * 16 + hh) * 65536 + (sbase + ml) * 64 + dk) = v;
    }
  }
}

// ---------------- flash attention: block = (b,h) x 128 q-rows; wave = 32q x 64keys ----------------
__global__ __launch_bounds__(256) void attn(const u16* __restrict__ Q, const u16* __restrict__ K,
                                            const u16* __restrict__ V, const float* __restrict__ emb,
                                            u16* __restrict__ ctx) {
  __shared__ __align__(16) u16 sK[64 * 64];
  __shared__ __align__(16) u16 sV[64 * 64];     // V^T tile [d][s_local]
  __shared__ __align__(16) u16 sP[128 * 72];    // P [qrow][key], stride 72 (144B, 16B aligned)
  __shared__ __align__(16) float4 bt4[1156];    // replicated bias*log2e
  const int tid = threadIdx.x, lane = tid & 63, wave = tid >> 6;
  const int l15 = lane & 15, quad = lane >> 4;
  const int bh = blockIdx.x, qt = blockIdx.y;
  const int h = bh & 15, b = bh >> 4;
  const u16* Qp = Q + bh * 65536 + qt * 8192;
  const u16* Kp = K + bh * 65536;
  const u16* Vp = V + bh * 65536;
  const int sx = l15 & 7;

  bf16x8 aq[2][2];
#pragma unroll
  for (int u = 0; u < 2; u++)
#pragma unroll
    for (int kk = 0; kk < 2; kk++)
      aq[u][kk] = *(const bf16x8*)(Qp + (wave * 32 + u * 16 + l15) * 64 + kk * 32 + quad * 8);

  for (int i = tid; i < 1156; i += 256) {
    int rp0 = i - 127 - qt * 128;
    float4 v;
    v.x = emb[t5_bucket(rp0)     * 16 + h] * LOG2E;
    v.y = emb[t5_bucket(rp0 + 1) * 16 + h] * LOG2E;
    v.z = emb[t5_bucket(rp0 + 2) * 16 + h] * LOG2E;
    v.w = emb[t5_bucket(rp0 + 3) * 16 + h] * LOG2E;
    bt4[i] = v;
  }
  const float bias_pos = emb[31 * 16 + h] * LOG2E;  // rp >= 91
  const float bias_neg = emb[15 * 16 + h] * LOG2E;  // rp <= -91

  float2 ls2[2] = {{0.f, 0.f}, {0.f, 0.f}};
  f32x4 oc[2][4];
  const f32x4 vzero = {0.f, 0.f, 0.f, 0.f};
#pragma unroll
  for (int u = 0; u < 2; u++)
#pragma unroll
    for (int nt = 0; nt < 4; nt++) oc[u][nt] = vzero;

  __syncthreads();   // bt4 ready

#pragma unroll 1
  for (int j = 0; j < 16; j++) {
    const u16* Kj = Kp + j * 4096;
#pragma unroll
    for (int r = 0; r < 2; r++) {
      int cb = r * 256 + wave * 64;
      int cc = cb + lane;
      int row = cc >> 3, c8 = (cc & 7) ^ (row & 7);
      gld16(sK + cb * 8, Kj + row * 64 + c8 * 8);
      gld16(sV + cb * 8, Vp + row * 1024 + j * 64 + c8 * 8);
    }
    __syncthreads();

    // S^T = K.Q^T + bias  (lane: key = mt*16+quad*4+reg, qrow = u*16+l15)
    f32x4 sc[4][2];
    const int rp_min = j * 64 - qt * 128 - 127;
    const int rp_max = j * 64 + 63 - qt * 128;
    if (rp_min >= 91) {
#pragma unroll
      for (int mt = 0; mt < 4; mt++)
#pragma unroll
        for (int u = 0; u < 2; u++) { sc[mt][u][0] = bias_pos; sc[mt][u][1] = bias_pos; sc[mt][u][2] = bias_pos; sc[mt][u][3] = bias_pos; }
    } else if (rp_max <= -91) {
#pragma unroll
      for (int mt = 0; mt < 4; mt++)
#pragma unroll
        for (int u = 0; u < 2; u++) { sc[mt][u][0] = bias_neg; sc[mt][u][1] = bias_neg; sc[mt][u][2] = bias_neg; sc[mt][u][3] = bias_neg; }
    } else {
#pragma unroll
      for (int mt = 0; mt < 4; mt++)
#pragma unroll
        for (int u = 0; u < 2; u++) {
          int idx = j * 64 + mt * 16 + quad * 4 - wave * 32 - u * 16 - l15 + 127;
          float4 bv4 = bt4[idx];
          sc[mt][u][0] = bv4.x; sc[mt][u][1] = bv4.y; sc[mt][u][2] = bv4.z; sc[mt][u][3] = bv4.w;
        }
    }
#pragma unroll
    for (int kk = 0; kk < 2; kk++) {
      bf16x8 ak[4];
      int g8 = kk * 4 + quad;
#pragma unroll
      for (int mt = 0; mt < 4; mt++)
        ak[mt] = *(const bf16x8*)(sK + (mt * 16 + l15) * 64 + (g8 ^ sx) * 8);
#pragma unroll
      for (int mt = 0; mt < 4; mt++)
#pragma unroll
        for (int u = 0; u < 2; u++)
          sc[mt][u] = MFMA16(ak[mt], aq[u][kk], sc[mt][u]);
    }

    // softmax: truncate-to-bf16 P; lsum accumulated from TRUNCATED values so the
    // numerator/denominator bias cancels in the final ratio (error ~= RNE's).
#pragma unroll
    for (int u = 0; u < 2; u++) {
      const int prow = wave * 32 + u * 16 + l15;
#pragma unroll
      for (int mt = 0; mt < 4; mt++) {
        u32 b0 = __float_as_uint(__builtin_amdgcn_exp2f(sc[mt][u][0]));
        u32 b1 = __float_as_uint(__builtin_amdgcn_exp2f(sc[mt][u][1]));
        u32 b2 = __float_as_uint(__builtin_amdgcn_exp2f(sc[mt][u][2]));
        u32 b3 = __float_as_uint(__builtin_amdgcn_exp2f(sc[mt][u][3]));
        u32 t0 = b0 & 0xFFFF0000u, t1 = b1 & 0xFFFF0000u;
        u32 t2 = b2 & 0xFFFF0000u, t3 = b3 & 0xFFFF0000u;
        ls2[u].x += __uint_as_float(t0) + __uint_as_float(t2);
        ls2[u].y += __uint_as_float(t1) + __uint_as_float(t3);
        uint2 pk;
        pk.x = (t0 >> 16) | t1;
        pk.y = (t2 >> 16) | t3;
        *(uint2*)(sP + prow * 72 + mt * 16 + quad * 4) = pk;
      }
    }
    asm volatile("s_waitcnt lgkmcnt(0)" ::: "memory");   // wave-private P write->read

    // O += P.V
#pragma unroll
    for (int kk = 0; kk < 2; kk++) {
      bf16x8 ap[2];
      int g8 = kk * 4 + quad;
#pragma unroll
      for (int u = 0; u < 2; u++)
        ap[u] = *(const bf16x8*)(sP + (wave * 32 + u * 16 + l15) * 72 + kk * 32 + quad * 8);
#pragma unroll
      for (int nt = 0; nt < 4; nt++) {
        bf16x8 bv = *(const bf16x8*)(sV + (nt * 16 + l15) * 64 + (g8 ^ sx) * 8);
#pragma unroll
        for (int u = 0; u < 2; u++)
          oc[u][nt] = MFMA16(ap[u], bv, oc[u][nt]);
      }
    }
    __syncthreads();
  }

  float lsum[2];
#pragma unroll
  for (int u = 0; u < 2; u++) {
    lsum[u] = ls2[u].x + ls2[u].y;
    lsum[u] += __shfl_xor(lsum[u], 16, 64);
    lsum[u] += __shfl_xor(lsum[u], 32, 64);
  }
  float linv[2][4];
#pragma unroll
  for (int u = 0; u < 2; u++)
#pragma unroll
    for (int reg = 0; reg < 4; reg++)
      linv[u][reg] = __builtin_amdgcn_rcpf(__shfl(lsum[u], quad * 4 + reg, 64));

  u16* cb2 = ctx + b * 1048576 + (qt * 128 + wave * 32) * 1024 + h * 64;
#pragma unroll
  for (int u = 0; u < 2; u++)
#pragma unroll
    for (int nt = 0; nt < 4; nt++)
#pragma unroll
      for (int reg = 0; reg < 4; reg++)
        cb2[(u * 16 + quad * 4 + reg) * 1024 + nt * 16 + l15] = f2bf(oc[u][nt][reg] * linv[u][reg]);
}

// ---------------- out-proj GEMM: 128m x 64n tiles, fp32 out ----------------
__global__ __launch_bounds__(256) void gemm_o(const u16* __restrict__ A,
                                              const u16* __restrict__ Bt,
                                              float* __restrict__ O) {
  __shared__ __align__(16) u16 sA[128 * 64];
  __shared__ __align__(16) u16 sB[64 * 64];
  const int tid = threadIdx.x, lane = tid & 63, wave = tid >> 6;
  const int l15 = lane & 15, quad = lane >> 4;
  const int wm = (wave >> 1) * 64, wn = (wave & 1) * 32;
  const int m0 = blockIdx.x * 128, n0 = blockIdx.y * 64;

  f32x4 acc[4][2];
  const f32x4 vz = {0.f, 0.f, 0.f, 0.f};
#pragma unroll
  for (int i = 0; i < 4; i++) { acc[i][0] = vz; acc[i][1] = vz; }

  const int sx = l15 & 7;

  for (int kt = 0; kt < 16; kt++) {
    const int ka = kt * 64;
#pragma unroll
    for (int r = 0; r < 4; r++) {
      int cb = r * 256 + wave * 64;
      int cc = cb + lane;
      int row = cc >> 3, c8 = (cc & 7) ^ (row & 7);
      gld16(sA + cb * 8, A + (m0 + row) * 1024 + ka + c8 * 8);
    }
#pragma unroll
    for (int r = 0; r < 2; r++) {
      int cb = r * 256 + wave * 64;
      int cc = cb + lane;
      int row = cc >> 3, c8 = (cc & 7) ^ (row & 7);
      gld16(sB + cb * 8, Bt + (n0 + row) * 1024 + ka + c8 * 8);
    }
    __syncthreads();
#pragma unroll
    for (int kk = 0; kk < 2; kk++) {
      bf16x8 af[4], bg[2];
      int g8 = kk * 4 + quad;
#pragma unroll
      for (int mt = 0; mt < 4; mt++)
        af[mt] = *(const bf16x8*)(sA + (wm + mt * 16 + l15) * 64 + (g8 ^ sx) * 8);
#pragma unroll
      for (int nt = 0; nt < 2; nt++)
        bg[nt] = *(const bf16x8*)(sB + (wn + nt * 16 + l15) * 64 + (g8 ^ sx) * 8);
#pragma unroll
      for (int mt = 0; mt < 4; mt++)
#pragma unroll
        for (int nt = 0; nt < 2; nt++)
          acc[mt][nt] = MFMA16(af[mt], bg[nt], acc[mt][nt]);
    }
    __syncthreads();
  }

#pragma unroll
  for (int mt = 0; mt < 4; mt++)
#pragma unroll
    for (int nt = 0; nt < 2; nt++)
#pragma unroll
      for (int reg = 0; reg < 4; reg++) {
        int row = m0 + wm + mt * 16 + quad * 4 + reg;
        int col = n0 + wn + nt * 16 + l15;
        O[row * 1024 + col] = acc[mt][nt][reg];
      }
}

extern "C" void kernel_launch(void* const* d_in, const int* in_sizes, int n_in,
                              void* d_out, int out_size, void* d_ws, size_t ws_size,
                              hipStream_t stream) {
  (void)in_sizes; (void)n_in; (void)out_size; (void)ws_size;
  const float* X   = (const float*)d_in[0];
  const float* Wq  = (const float*)d_in[1];
  const float* Wk  = (const float*)d_in[2];
  const float* Wv  = (const float*)d_in[3];
  const float* Wo  = (const float*)d_in[4];
  const float* emb = (const float*)d_in[5];

  char* ws = (char*)d_ws;
  u16* Xb  = (u16*)(ws);                              // 8 MB: X bf16 [4096][1024]
  u16* Wt  = (u16*)(ws + (8u  << 20));                // 8 MB: Wq^T,Wk^T,Wv^T,Wo^T bf16
  u16* Qb  = (u16*)(ws + (16u << 20));                // 8+8+8 MB: Q(log2e-scaled), K, Vt
  u16* Ctx = (u16*)(ws + (40u << 20));                // 8 MB: attention output bf16

  prep<<<1024, 256, 0, stream>>>((const float4*)X, (ushort4*)Xb, Wq, Wk, Wv, Wo, Wt);
  gemm128<<<dim3(24, 32), 256, 0, stream>>>(Xb, Wt, Qb);
  attn<<<dim3(64, 8), 256, 0, stream>>>(Qb, Qb + 4194304, Qb + 2 * 4194304, emb, Ctx);
  gemm_o<<<dim3(32, 16), 256, 0, stream>>>(Ctx, Wt + 3 * 1048576, (float*)d_out);
}